// Round 10
// baseline (573.621 us; speedup 1.0000x reference)
//
#include <hip/hip_runtime.h>
#include <hip/hip_fp16.h>
#include <stdint.h>

#define NN   10000
#define NE   320000
#define HID  256
#define MB   64                  // edges per block in MFMA edge kernels
#define NEB  (NE/MB)             // 5000 blocks (exact)
#define MT   32                  // rows per block in dense GEMM
#define NMT  313                 // ceil(10000/32)

#define DG_PLAIN 0
#define DG_SPLIT 1
#define DG_2A    2

typedef __attribute__((ext_vector_type(8))) short short8;
typedef __attribute__((ext_vector_type(4))) float f32x4;

struct CvtPtrs { const float* p[15]; };

__device__ __forceinline__ float silu_f(float v){ return v / (1.f + __expf(-v)); }
__device__ __forceinline__ float sigm_f(float v){ return 1.f / (1.f + __expf(-v)); }
__device__ __forceinline__ __half2 silu2(__half2 x){
    __half2 e = h2exp2(__hmul2(x, __float2half2_rn(-1.442695041f)));
    __half2 d = __hadd2(e, __float2half2_rn(1.0f));
    return __hmul2(x, h2rcp(d));
}
__device__ __forceinline__ __half2 h2shfl_xor_add(__half2 v, int m){
    int pi = *(int*)&v;
    pi = __shfl_xor(pi, m, 64);
    __half2 q = *(__half2*)&pi;
    return __hadd2(v, q);
}
// XCD-aware swizzle: consecutive logical blocks land on the SAME XCD so the
// shared agg/Hrow lines stay in one per-XCD L2 (dispatch is round-robin i%8).
__device__ __forceinline__ int xcd_logical(int bid, int nblk){
    int per = nblk >> 3;                 // nblk divisible by 8
    return (bid & 7) * per + (bid >> 3);
}

// ---- CSR build -------------------------------------------------------------
__global__ __launch_bounds__(256) void k_count(const int* __restrict__ row, int* __restrict__ cnt){
    int e = blockIdx.x * 256 + threadIdx.x;
    if (e < NE) atomicAdd(&cnt[row[e]], 1);
}

__global__ __launch_bounds__(1024) void k_scan(const int* __restrict__ cnt, int* __restrict__ rs, int* __restrict__ cur){
    __shared__ int sums[1024];
    const int PER = 10;                 // 1024*10 = 10240 >= NN
    int t = threadIdx.x;
    int base = t * PER;
    int s = 0;
    for (int i = 0; i < PER; i++){
        int idx = base + i;
        s += (idx < NN) ? cnt[idx] : 0;
    }
    sums[t] = s;
    __syncthreads();
    for (int off = 1; off < 1024; off <<= 1){
        int v = (t >= off) ? sums[t - off] : 0;
        __syncthreads();
        sums[t] += v;
        __syncthreads();
    }
    int run = (t == 0) ? 0 : sums[t - 1];
    for (int i = 0; i < PER; i++){
        int idx = base + i;
        if (idx < NN){
            int c = cnt[idx];
            rs[idx] = run;
            cur[idx] = run;
            run += c;
        }
    }
    if (t == 1023) rs[NN] = sums[1023];
}

__global__ __launch_bounds__(256) void k_fill(const int* __restrict__ row, int* __restrict__ cur, int* __restrict__ perm){
    int e = blockIdx.x * 256 + threadIdx.x;
    if (e < NE){
        int p = atomicAdd(&cur[row[e]], 1);
        perm[p] = e;
    }
}

// ---- combined prep ---------------------------------------------------------
// blocks [0,120): coalesced LDS-tiled transpose of 15 weight chunks into
//   MFMA-B-fragment order fp16. Block b: mat = b/8, kk = b%8.
// blocks [120,1370): h fp32 -> fp16 mirror.
__global__ __launch_bounds__(256) void k_prep(CvtPtrs pp, __half* __restrict__ dst,
                                              const float* __restrict__ hsrc, __half* __restrict__ h16){
    int bid = blockIdx.x, t = threadIdx.x;
    if (bid < 120){
        __shared__ __half lh[32 * 256];     // rows k=kk*32..+32, cols 0..255
        int mat = bid >> 3, kk = bid & 7;
        const float* src = pp.p[mat] + (size_t)kk * 32 * 256;
        #pragma unroll
        for (int i = 0; i < 32; i++)
            lh[i * 256 + t] = __float2half_rn(src[i * 256 + t]);   // coalesced
        __syncthreads();
        __half* db = dst + (size_t)mat * 65536 + kk * 512;
        int lane = t >> 2;
        int j0   = (t * 2) & 7;
        int i0   = (lane >> 4) * 8 + j0;    // k - kk*32
        int ncol = lane & 15;
        #pragma unroll
        for (int nt = 0; nt < 16; nt++){
            __half v0 = lh[i0 * 256 + nt * 16 + ncol];
            __half v1 = lh[(i0 + 1) * 256 + nt * 16 + ncol];
            unsigned int u = (unsigned int)*(unsigned short*)&v0 |
                             ((unsigned int)*(unsigned short*)&v1 << 16);
            *(unsigned int*)&db[nt * 4096 + t * 2] = u;            // coalesced
        }
    } else {
        int i = ((bid - 120) * 256 + t) * 8;      // NN*HID = 2.56M
        float4 f0 = *(const float4*)&hsrc[i];
        float4 f1 = *(const float4*)&hsrc[i + 4];
        uint4 o; __half2* op = (__half2*)&o;
        op[0] = __float22half2_rn(make_float2(f0.x, f0.y));
        op[1] = __float22half2_rn(make_float2(f0.z, f0.w));
        op[2] = __float22half2_rn(make_float2(f1.x, f1.y));
        op[3] = __float22half2_rn(make_float2(f1.z, f1.w));
        *(uint4*)&h16[i] = o;
    }
}

// ---- MFMA dense GEMM (XOR-swizzled LDS, M=32 tile, 8 blocks/CU) -----------
__global__ __launch_bounds__(256, 8) void k_dgemm(
        const __half* __restrict__ A1, const float* __restrict__ A2f,
        const __half* __restrict__ wpool, int wAidx, int wBidx,
        const float* __restrict__ bias, const __half* __restrict__ R16,
        float* __restrict__ out32, __half* __restrict__ out16,
        __half* __restrict__ outB16, float* __restrict__ zbuf, int mode, int act){
    __shared__ __half alds[MT * 256];
    int tid = threadIdx.x;
    int lid = tid & 63, w = tid >> 6;
    int quad = lid >> 4, l15 = lid & 15;
    int rb = blockIdx.x * MT;
    int by = blockIdx.y;
    int xorv = l15 & 7;

    // folded aggb zeroing (SPLIT layers only): each (row,col) zeroed once
    if (mode == DG_SPLIT && zbuf && by < 2){
        int sr2 = tid >> 5, cz = (tid & 31) * 4;
        #pragma unroll
        for (int it = 0; it < MT / 8; it++){
            int rg = rb + it * 8 + sr2;
            if (rg < NN){
                float4 z4 = {0.f, 0.f, 0.f, 0.f};
                *(float4*)&zbuf[(size_t)rg * HID + by * 128 + cz] = z4;
            }
        }
    }

    float bv[2]; int cg0[2];
    #pragma unroll
    for (int n = 0; n < 2; n++){
        int cg = by * 128 + w * 32 + n * 16 + l15;
        cg0[n] = cg;
        bv[n] = (bias && cg < 256) ? bias[cg] : 0.f;
    }
    f32x4 acc[2][2];
    #pragma unroll
    for (int m = 0; m < 2; m++)
        #pragma unroll
        for (int n = 0; n < 2; n++){ f32x4 z = {bv[n], bv[n], bv[n], bv[n]}; acc[m][n] = z; }

    int npass = (mode == DG_2A) ? 2 : 1;
    int sr = tid >> 5;
    int c0 = (tid & 31) * 8;                       // logical column
    int pc = (((tid & 31) ^ sr) * 8);              // physical (swizzled) LDS column
    for (int pass = 0; pass < npass; pass++){
        if (pass) __syncthreads();
        int widx, byl = by;
        if (mode == DG_SPLIT){ if (by >= 2){ widx = wBidx; byl = by - 2; } else widx = wAidx; }
        else widx = pass ? wBidx : wAidx;
        const short8* bbase = (const short8*)(wpool + (size_t)widx * 65536);

        if (pass == 0){
            #pragma unroll
            for (int it = 0; it < MT / 8; it++){
                int r = it * 8 + sr;
                int rr = rb + r; if (rr > NN - 1) rr = NN - 1;
                *(uint4*)&alds[r * 256 + pc] = *(const uint4*)&A1[(size_t)rr * HID + c0];
            }
        } else {
            #pragma unroll
            for (int it = 0; it < MT / 8; it++){
                int r = it * 8 + sr;
                int rr = rb + r; if (rr > NN - 1) rr = NN - 1;
                float4 f0 = *(const float4*)&A2f[(size_t)rr * HID + c0];
                float4 f1 = *(const float4*)&A2f[(size_t)rr * HID + c0 + 4];
                uint4 o; __half2* op = (__half2*)&o;
                op[0] = __float22half2_rn(make_float2(f0.x, f0.y));
                op[1] = __float22half2_rn(make_float2(f0.z, f0.w));
                op[2] = __float22half2_rn(make_float2(f1.x, f1.y));
                op[3] = __float22half2_rn(make_float2(f1.z, f1.w));
                *(uint4*)&alds[r * 256 + pc] = o;
            }
        }
        __syncthreads();
        #pragma unroll
        for (int kk = 0; kk < 8; kk++){
            short8 bf[2];
            #pragma unroll
            for (int n = 0; n < 2; n++)
                bf[n] = bbase[((byl * 8 + w * 2 + n) * 8 + kk) * 64 + lid];
            #pragma unroll
            for (int m = 0; m < 2; m++){
                const short8 af = *(const short8*)&alds[(m * 16 + l15) * 256 + (((kk * 4 + quad) ^ xorv) * 8)];
                #pragma unroll
                for (int n = 0; n < 2; n++)
                    acc[m][n] = __builtin_amdgcn_mfma_f32_16x16x32_f16(af, bf[n], acc[m][n], 0, 0, 0);
            }
        }
    }
    #pragma unroll
    for (int n = 0; n < 2; n++){
        int cg = cg0[n];
        #pragma unroll
        for (int m = 0; m < 2; m++){
            #pragma unroll
            for (int r = 0; r < 4; r++){
                int rg = rb + m * 16 + quad * 4 + r;
                if (rg < NN){
                    float v = acc[m][n][r];
                    if (act) v = silu_f(v);
                    if (R16) v += __half2float(R16[(size_t)rg * HID + cg]);
                    if (mode == DG_SPLIT){
                        if (cg < 256) out16[(size_t)rg * HID + cg] = __float2half_rn(v);
                        else          outB16[(size_t)rg * HID + cg - 256] = __float2half_rn(v);
                    } else {
                        if (out32) out32[(size_t)rg * HID + cg] = v;
                        if (out16) out16[(size_t)rg * HID + cg] = __float2half_rn(v);
                    }
                }
            }
        }
    }
}

// ---- MFMA edge kernel (GCL): 64 perm-ordered edges per block --------------
__global__ __launch_bounds__(256, 4) void k_edge_mfma(
        const __half* __restrict__ HrowB, const __half* __restrict__ HcolB,
        const int* __restrict__ row, const int* __restrict__ col,
        const float* __restrict__ ea, const int* __restrict__ perm,
        const __half* __restrict__ w2f,
        const float* __restrict__ w512, const float* __restrict__ w513,
        const float* __restrict__ eb2, const float* __restrict__ aw, const float* __restrict__ ab,
        float* __restrict__ agg){
    __shared__ __half vlds[MB * 256];
    __shared__ unsigned int attp2[4][MB / 2];
    __shared__ float attf[MB];
    __shared__ int   nrows[MB];
    __shared__ int   cids[MB];
    __shared__ float ea0s[MB], ea1s[MB];

    int tid = threadIdx.x;
    int e0  = xcd_logical(blockIdx.x, NEB) * MB;
    float ab0 = ab[0];
    if (tid < MB){
        int eid = perm[e0 + tid];
        nrows[tid] = row[eid];
        cids[tid]  = col[eid];
        ea0s[tid]  = ea[eid * 2 + 0];
        ea1s[tid]  = ea[eid * 2 + 1];
    }
    __syncthreads();
    {   // staging with full gather-hoist: all 16 loads in flight before compute
        int sr = tid >> 5;
        int c0 = (tid & 31) * 8;
        int pc = ((tid & 31) ^ sr) * 8;            // swizzled LDS chunk
        int nidv[8], cidv[8];
        float ea0v[8], ea1v[8];
        #pragma unroll
        for (int it = 0; it < 8; it++){
            int r = it * 8 + sr;
            nidv[it] = nrows[r]; cidv[it] = cids[r];
            ea0v[it] = ea0s[r];  ea1v[it] = ea1s[r];
        }
        uint4 hrv[8], hcv[8];
        #pragma unroll
        for (int it = 0; it < 8; it++){
            hrv[it] = *(const uint4*)&HrowB[(size_t)nidv[it] * HID + c0];
            hcv[it] = *(const uint4*)&HcolB[(size_t)cidv[it] * HID + c0];
        }
        float4 wa = *(const float4*)&w512[c0];
        float4 wb = *(const float4*)&w512[c0 + 4];
        float4 ua = *(const float4*)&w513[c0];
        float4 ub = *(const float4*)&w513[c0 + 4];
        __half2 w5h[4] = {__float22half2_rn(make_float2(wa.x, wa.y)), __float22half2_rn(make_float2(wa.z, wa.w)),
                          __float22half2_rn(make_float2(wb.x, wb.y)), __float22half2_rn(make_float2(wb.z, wb.w))};
        __half2 w6h[4] = {__float22half2_rn(make_float2(ua.x, ua.y)), __float22half2_rn(make_float2(ua.z, ua.w)),
                          __float22half2_rn(make_float2(ub.x, ub.y)), __float22half2_rn(make_float2(ub.z, ub.w))};
        #pragma unroll
        for (int it = 0; it < 8; it++){
            int r = it * 8 + sr;
            __half2 e0h = __float2half2_rn(ea0v[it]);
            __half2 e1h = __float2half2_rn(ea1v[it]);
            const __half2* hrp = (const __half2*)&hrv[it];
            const __half2* hcp = (const __half2*)&hcv[it];
            uint4 o; __half2* op = (__half2*)&o;
            #pragma unroll
            for (int q = 0; q < 4; q++){
                __half2 t = __hadd2(hrp[q], hcp[q]);
                t = __hfma2(e0h, w5h[q], t);
                t = __hfma2(e1h, w6h[q], t);
                op[q] = silu2(t);
            }
            *(uint4*)&vlds[r * 256 + pc] = o;
        }
    }
    __syncthreads();

    int lid = tid & 63, w = tid >> 6;
    int quad = lid >> 4, l15 = lid & 15;
    int xorv = l15 & 7;

    float b2v[4]; __half2 aw2[4];
    #pragma unroll
    for (int n = 0; n < 4; n++){
        int cg = w * 64 + n * 16 + l15;
        b2v[n] = eb2[cg];
        aw2[n] = __float2half2_rn(aw[cg]);
    }
    f32x4 acc[4][4];
    #pragma unroll
    for (int m = 0; m < 4; m++)
        #pragma unroll
        for (int n = 0; n < 4; n++){ f32x4 z = {b2v[n], b2v[n], b2v[n], b2v[n]}; acc[m][n] = z; }

    const short8* bbase = (const short8*)w2f;
    #pragma unroll
    for (int kk = 0; kk < 8; kk++){
        short8 bf[4];
        #pragma unroll
        for (int n = 0; n < 4; n++)
            bf[n] = bbase[((w * 4 + n) * 8 + kk) * 64 + lid];
        #pragma unroll
        for (int m = 0; m < 4; m++){
            const short8 af = *(const short8*)&vlds[(m * 16 + l15) * 256 + (((kk * 4 + quad) ^ xorv) * 8)];
            #pragma unroll
            for (int n = 0; n < 4; n++)
                acc[m][n] = __builtin_amdgcn_mfma_f32_16x16x32_f16(af, bf[n], acc[m][n], 0, 0, 0);
        }
    }

    // packed epilogue: mij = silu2(pack(acc)); attention partials in fp16
    __half2 mijp[4][4][2];          // [m][n][pair]: (r0,r1),(r2,r3)
    #pragma unroll
    for (int m = 0; m < 4; m++){
        __half2 p2a = __float2half2_rn(0.f), p2b = p2a;
        #pragma unroll
        for (int n = 0; n < 4; n++){
            __half2 ha = silu2(__float22half2_rn(make_float2(acc[m][n][0], acc[m][n][1])));
            __half2 hb = silu2(__float22half2_rn(make_float2(acc[m][n][2], acc[m][n][3])));
            mijp[m][n][0] = ha; mijp[m][n][1] = hb;
            p2a = __hfma2(ha, aw2[n], p2a);
            p2b = __hfma2(hb, aw2[n], p2b);
        }
        p2a = h2shfl_xor_add(p2a, 1); p2a = h2shfl_xor_add(p2a, 2);
        p2a = h2shfl_xor_add(p2a, 4); p2a = h2shfl_xor_add(p2a, 8);
        p2b = h2shfl_xor_add(p2b, 1); p2b = h2shfl_xor_add(p2b, 2);
        p2b = h2shfl_xor_add(p2b, 4); p2b = h2shfl_xor_add(p2b, 8);
        if (l15 == 0){
            attp2[w][m * 8 + quad * 2 + 0] = *(unsigned int*)&p2a;
            attp2[w][m * 8 + quad * 2 + 1] = *(unsigned int*)&p2b;
        }
    }
    __syncthreads();
    if (tid < MB){
        int pr = tid >> 1;
        unsigned int u0 = attp2[0][pr], u1 = attp2[1][pr], u2 = attp2[2][pr], u3 = attp2[3][pr];
        __half2 h0 = *(__half2*)&u0, h1 = *(__half2*)&u1, h2 = *(__half2*)&u2, h3 = *(__half2*)&u3;
        float lo = __low2float(h0) + __low2float(h1) + __low2float(h2) + __low2float(h3);
        float hi = __high2float(h0) + __high2float(h1) + __high2float(h2) + __high2float(h3);
        float a0 = ((tid & 1) ? hi : lo) + ab0;
        attf[tid] = 0.01f * sigm_f(a0);     // fold /NORM_FACTOR into att
    }
    __syncthreads();

    // segment-sum agg (rows CSR-sorted); fast path: whole 16-tile one segment
    for (int m = 0; m < 4; m++){
        int mb = m * 16;
        __half2 at2a = __float22half2_rn(make_float2(attf[mb + quad * 4 + 0], attf[mb + quad * 4 + 1]));
        __half2 at2b = __float22half2_rn(make_float2(attf[mb + quad * 4 + 2], attf[mb + quad * 4 + 3]));
        int rA = nrows[mb], rB = nrows[mb + 15];
        if (rA == rB){
            #pragma unroll
            for (int n = 0; n < 4; n++){
                __half2 s2 = __hmul2(mijp[m][n][0], at2a);
                s2 = __hfma2(mijp[m][n][1], at2b, s2);
                float s = __low2float(s2) + __high2float(s2);
                s += __shfl_xor(s, 16);
                s += __shfl_xor(s, 32);
                if (lid < 16)
                    atomicAdd(&agg[(size_t)rA * HID + w * 64 + n * 16 + lid], s);
            }
        } else {
            float ef[4][4]; int nv[4];
            #pragma unroll
            for (int r = 0; r < 4; r++) nv[r] = nrows[mb + quad * 4 + r];
            #pragma unroll
            for (int n = 0; n < 4; n++){
                __half2 ea2 = __hmul2(mijp[m][n][0], at2a);
                __half2 eb2h = __hmul2(mijp[m][n][1], at2b);
                ef[n][0] = __low2float(ea2);  ef[n][1] = __high2float(ea2);
                ef[n][2] = __low2float(eb2h); ef[n][3] = __high2float(eb2h);
            }
            int myn = nrows[mb + l15];
            int t16 = 0;
            while (t16 < 16){
                int tgt = nrows[mb + t16];
                unsigned long long bal = __ballot((lid < 16) && (lid > t16) && (myn != tgt));
                int nxt = bal ? (__ffsll((unsigned long long)bal) - 1) : 16;
                #pragma unroll
                for (int n = 0; n < 4; n++){
                    float s = 0.f;
                    #pragma unroll
                    for (int r = 0; r < 4; r++)
                        s += (nv[r] == tgt) ? ef[n][r] : 0.f;
                    s += __shfl_xor(s, 16);
                    s += __shfl_xor(s, 32);
                    if (lid < 16)
                        atomicAdd(&agg[(size_t)tgt * HID + w * 64 + n * 16 + lid], s);
                }
                t16 = nxt;
            }
        }
    }
}

// ---- MFMA coord kernel: same GEMM, epilogue -> per-edge phi ---------------
__global__ __launch_bounds__(256, 4) void k_coord_mfma(
        const __half* __restrict__ CrowB, const __half* __restrict__ CcolB,
        const int* __restrict__ row, const int* __restrict__ col,
        const float* __restrict__ ea, const int* __restrict__ perm,
        const __half* __restrict__ w2f,
        const float* __restrict__ w512, const float* __restrict__ w513,
        const float* __restrict__ cb2, const float* __restrict__ cw3,
        float* __restrict__ phi){
    __shared__ __half vlds[MB * 256];
    __shared__ unsigned int pp2[4][MB / 2];
    __shared__ int   nrows[MB];
    __shared__ int   cids[MB];
    __shared__ float ea0s[MB], ea1s[MB];

    int tid = threadIdx.x;
    int e0  = xcd_logical(blockIdx.x, NEB) * MB;
    if (tid < MB){
        int eid = perm[e0 + tid];
        nrows[tid] = row[eid];
        cids[tid]  = col[eid];
        ea0s[tid]  = ea[eid * 2 + 0];
        ea1s[tid]  = ea[eid * 2 + 1];
    }
    __syncthreads();
    {   // staging with full gather-hoist
        int sr = tid >> 5;
        int c0 = (tid & 31) * 8;
        int pc = ((tid & 31) ^ sr) * 8;
        int nidv[8], cidv[8];
        float ea0v[8], ea1v[8];
        #pragma unroll
        for (int it = 0; it < 8; it++){
            int r = it * 8 + sr;
            nidv[it] = nrows[r]; cidv[it] = cids[r];
            ea0v[it] = ea0s[r];  ea1v[it] = ea1s[r];
        }
        uint4 hrv[8], hcv[8];
        #pragma unroll
        for (int it = 0; it < 8; it++){
            hrv[it] = *(const uint4*)&CrowB[(size_t)nidv[it] * HID + c0];
            hcv[it] = *(const uint4*)&CcolB[(size_t)cidv[it] * HID + c0];
        }
        float4 wa = *(const float4*)&w512[c0];
        float4 wb = *(const float4*)&w512[c0 + 4];
        float4 ua = *(const float4*)&w513[c0];
        float4 ub = *(const float4*)&w513[c0 + 4];
        __half2 w5h[4] = {__float22half2_rn(make_float2(wa.x, wa.y)), __float22half2_rn(make_float2(wa.z, wa.w)),
                          __float22half2_rn(make_float2(wb.x, wb.y)), __float22half2_rn(make_float2(wb.z, wb.w))};
        __half2 w6h[4] = {__float22half2_rn(make_float2(ua.x, ua.y)), __float22half2_rn(make_float2(ua.z, ua.w)),
                          __float22half2_rn(make_float2(ub.x, ub.y)), __float22half2_rn(make_float2(ub.z, ub.w))};
        #pragma unroll
        for (int it = 0; it < 8; it++){
            int r = it * 8 + sr;
            __half2 e0h = __float2half2_rn(ea0v[it]);
            __half2 e1h = __float2half2_rn(ea1v[it]);
            const __half2* hrp = (const __half2*)&hrv[it];
            const __half2* hcp = (const __half2*)&hcv[it];
            uint4 o; __half2* op = (__half2*)&o;
            #pragma unroll
            for (int q = 0; q < 4; q++){
                __half2 t = __hadd2(hrp[q], hcp[q]);
                t = __hfma2(e0h, w5h[q], t);
                t = __hfma2(e1h, w6h[q], t);
                op[q] = silu2(t);
            }
            *(uint4*)&vlds[r * 256 + pc] = o;
        }
    }
    __syncthreads();

    int lid = tid & 63, w = tid >> 6;
    int quad = lid >> 4, l15 = lid & 15;
    int xorv = l15 & 7;

    float b2v[4]; __half2 w32[4];
    #pragma unroll
    for (int n = 0; n < 4; n++){
        int cg = w * 64 + n * 16 + l15;
        b2v[n] = cb2[cg];
        w32[n] = __float2half2_rn(cw3[cg]);
    }
    f32x4 acc[4][4];
    #pragma unroll
    for (int m = 0; m < 4; m++)
        #pragma unroll
        for (int n = 0; n < 4; n++){ f32x4 z = {b2v[n], b2v[n], b2v[n], b2v[n]}; acc[m][n] = z; }

    const short8* bbase = (const short8*)w2f;
    #pragma unroll
    for (int kk = 0; kk < 8; kk++){
        short8 bf[4];
        #pragma unroll
        for (int n = 0; n < 4; n++)
            bf[n] = bbase[((w * 4 + n) * 8 + kk) * 64 + lid];
        #pragma unroll
        for (int m = 0; m < 4; m++){
            const short8 af = *(const short8*)&vlds[(m * 16 + l15) * 256 + (((kk * 4 + quad) ^ xorv) * 8)];
            #pragma unroll
            for (int n = 0; n < 4; n++)
                acc[m][n] = __builtin_amdgcn_mfma_f32_16x16x32_f16(af, bf[n], acc[m][n], 0, 0, 0);
        }
    }

    #pragma unroll
    for (int m = 0; m < 4; m++){
        __half2 p2a = __float2half2_rn(0.f), p2b = p2a;
        #pragma unroll
        for (int n = 0; n < 4; n++){
            __half2 ha = silu2(__float22half2_rn(make_float2(acc[m][n][0], acc[m][n][1])));
            __half2 hb = silu2(__float22half2_rn(make_float2(acc[m][n][2], acc[m][n][3])));
            p2a = __hfma2(ha, w32[n], p2a);
            p2b = __hfma2(hb, w32[n], p2b);
        }
        p2a = h2shfl_xor_add(p2a, 1); p2a = h2shfl_xor_add(p2a, 2);
        p2a = h2shfl_xor_add(p2a, 4); p2a = h2shfl_xor_add(p2a, 8);
        p2b = h2shfl_xor_add(p2b, 1); p2b = h2shfl_xor_add(p2b, 2);
        p2b = h2shfl_xor_add(p2b, 4); p2b = h2shfl_xor_add(p2b, 8);
        if (l15 == 0){
            pp2[w][m * 8 + quad * 2 + 0] = *(unsigned int*)&p2a;
            pp2[w][m * 8 + quad * 2 + 1] = *(unsigned int*)&p2b;
        }
    }
    __syncthreads();
    if (tid < MB){
        int pr = tid >> 1;
        unsigned int u0 = pp2[0][pr], u1 = pp2[1][pr], u2 = pp2[2][pr], u3 = pp2[3][pr];
        __half2 h0 = *(__half2*)&u0, h1 = *(__half2*)&u1, h2 = *(__half2*)&u2, h3 = *(__half2*)&u3;
        float lo = __low2float(h0) + __low2float(h1) + __low2float(h2) + __low2float(h3);
        float hi = __high2float(h0) + __high2float(h1) + __high2float(h2) + __high2float(h3);
        phi[e0 + tid] = (tid & 1) ? hi : lo;
    }
}

// ---- coordinate segment-sum: one wave per node ----------------------------
__global__ __launch_bounds__(64) void k_xupd(const float* __restrict__ x, const float* __restrict__ phi,
                                             const int* __restrict__ col, const int* __restrict__ perm,
                                             const int* __restrict__ rs, float* __restrict__ xout){
    int n = blockIdx.x, lid = threadIdx.x;
    int s = rs[n], e = rs[n + 1];
    float x0 = x[n * 3 + 0], x1 = x[n * 3 + 1], x2 = x[n * 3 + 2];
    float tx = 0.f, ty = 0.f, tz = 0.f;
    for (int i = s + lid; i < e; i += 64){
        int eid = perm[i];
        int c = col[eid];
        float d0 = x0 - x[c * 3 + 0];
        float d1 = x1 - x[c * 3 + 1];
        float d2 = x2 - x[c * 3 + 2];
        float r2 = d0 * d0 + d1 * d1 + d2 * d2;
        float f  = phi[i] / (sqrtf(r2 + 1e-8f) + 1.f);   // NORM_CONST = 1
        tx += d0 * f; ty += d1 * f; tz += d2 * f;
    }
    for (int o = 32; o; o >>= 1){
        tx += __shfl_down(tx, o);
        ty += __shfl_down(ty, o);
        tz += __shfl_down(tz, o);
    }
    if (lid == 0){
        xout[n * 3 + 0] = x0 + 0.01f * tx;
        xout[n * 3 + 1] = x1 + 0.01f * ty;
        xout[n * 3 + 2] = x2 + 0.01f * tz;
    }
}

// ---------------------------------------------------------------------------
extern "C" void kernel_launch(void* const* d_in, const int* in_sizes, int n_in,
                              void* d_out, int out_size, void* d_ws, size_t ws_size,
                              hipStream_t stream){
    const float* h  = (const float*)d_in[0];
    const float* x  = (const float*)d_in[1];
    const int*   ei = (const int*)d_in[2];
    const float* ea = (const float*)d_in[3];
    const int* rowp = ei;
    const int* colp = ei + NE;

    const float* ew1[2] = {(const float*)d_in[4],  (const float*)d_in[14]};
    const float* eb1[2] = {(const float*)d_in[5],  (const float*)d_in[15]};
    const float* ew2[2] = {(const float*)d_in[6],  (const float*)d_in[16]};
    const float* eb2[2] = {(const float*)d_in[7],  (const float*)d_in[17]};
    const float* nw1[2] = {(const float*)d_in[8],  (const float*)d_in[18]};
    const float* nb1[2] = {(const float*)d_in[9],  (const float*)d_in[19]};
    const float* nw2[2] = {(const float*)d_in[10], (const float*)d_in[20]};
    const float* nb2[2] = {(const float*)d_in[11], (const float*)d_in[21]};
    const float* aw[2]  = {(const float*)d_in[12], (const float*)d_in[22]};
    const float* ab[2]  = {(const float*)d_in[13], (const float*)d_in[23]};
    const float* cw1 = (const float*)d_in[24];
    const float* cb1 = (const float*)d_in[25];
    const float* cw2 = (const float*)d_in[26];
    const float* cb2 = (const float*)d_in[27];
    const float* cw3 = (const float*)d_in[28];

    char* w = (char*)d_ws;
    auto alloc = [&](size_t bytes){ void* p = (void*)w; w += (bytes + 255) & ~((size_t)255); return p; };
    int* rs    = (int*)alloc((NN + 1) * sizeof(int));
    int* cur   = (int*)alloc(NN * sizeof(int));
    int* perm  = (int*)alloc(NE * sizeof(int));
    __half* HrowB = (__half*)alloc((size_t)NN * HID * sizeof(__half));
    __half* HcolB = (__half*)alloc((size_t)NN * HID * sizeof(__half));
    float*  aggb  = (float*)alloc((size_t)NN * HID * sizeof(float));
    __half* wfrag = (__half*)alloc((size_t)15 * HID * HID * sizeof(__half));
    float*  phi   = (float*)alloc((size_t)NE * sizeof(float));
    __half* h16   = (__half*)alloc((size_t)NN * HID * sizeof(__half));
    __half* Tb16  = HrowB;   // HrowB dead after edge kernel; reuse for node-MLP hidden

    float* hout = (float*)d_out;            // [NN,HID]
    float* xout = hout + (size_t)NN * HID;  // [NN,3]

    // CSR build + conversions
    hipMemsetAsync(cur, 0, NN * sizeof(int), stream);
    k_count<<<(NE + 255) / 256, 256, 0, stream>>>(rowp, cur);
    k_scan<<<1, 1024, 0, stream>>>(cur, rs, cur);
    k_fill<<<(NE + 255) / 256, 256, 0, stream>>>(rowp, cur, perm);

    CvtPtrs cp;
    for (int l = 0; l < 2; l++){
        cp.p[l * 5 + 0] = ew1[l];
        cp.p[l * 5 + 1] = ew1[l] + 256 * HID;
        cp.p[l * 5 + 2] = nw1[l];
        cp.p[l * 5 + 3] = nw1[l] + 256 * HID;
        cp.p[l * 5 + 4] = nw2[l];
    }
    cp.p[10] = cw1;
    cp.p[11] = cw1 + 256 * HID;
    cp.p[12] = ew2[0];
    cp.p[13] = ew2[1];
    cp.p[14] = cw2;
    k_prep<<<1370, 256, 0, stream>>>(cp, wfrag, h, h16);

    dim3 g2(NMT, 2), g4(NMT, 4);
    for (int l = 0; l < 2; l++){
        // [Hrow|Hcol] = h@[ew1a|ew1b] (+eb1 on first half), fp16 outs; zeroes aggb
        k_dgemm<<<g4, 256, 0, stream>>>(h16, nullptr, wfrag, l * 5 + 0, l * 5 + 1,
                                        eb1[l], nullptr, nullptr, HrowB, HcolB, aggb, DG_SPLIT, 0);
        k_edge_mfma<<<NEB, 256, 0, stream>>>(HrowB, HcolB, rowp, colp, ea, perm,
                                             wfrag + (size_t)(12 + l) * HID * HID,
                                             ew1[l] + 512 * HID, ew1[l] + 513 * HID,
                                             eb2[l], aw[l], ab[l], aggb);
        // T = silu(h@nw1a + agg@nw1b + nb1)  -> fp16
        k_dgemm<<<g2, 256, 0, stream>>>(h16, aggb, wfrag, l * 5 + 2, l * 5 + 3,
                                        nb1[l], nullptr, nullptr, Tb16, nullptr, nullptr, DG_2A, 1);
        // h = h_old + T@nw2 + nb2  -> fp32 (d_out) + fp16 mirror (R16 = old h16)
        k_dgemm<<<g2, 256, 0, stream>>>(Tb16, nullptr, wfrag, l * 5 + 4, 0,
                                        nb2[l], h16, hout, h16, nullptr, nullptr, DG_PLAIN, 0);
    }
    // coord update
    k_dgemm<<<g4, 256, 0, stream>>>(h16, nullptr, wfrag, 10, 11,
                                    cb1, nullptr, nullptr, HrowB, HcolB, nullptr, DG_SPLIT, 0);
    k_coord_mfma<<<NEB, 256, 0, stream>>>(HrowB, HcolB, rowp, colp, ea, perm,
                                          wfrag + (size_t)14 * HID * HID,
                                          cw1 + 512 * HID, cw1 + 513 * HID,
                                          cb2, cw3, phi);
    k_xupd<<<NN, 64, 0, stream>>>(x, phi, colp, perm, rs, xout);
}

// Round 11
// 542.639 us; speedup vs baseline: 1.0571x; 1.0571x over previous
//
#include <hip/hip_runtime.h>
#include <hip/hip_fp16.h>
#include <stdint.h>

#define NN   10000
#define NE   320000
#define HID  256
#define MB   64                  // edges per block in MFMA edge kernels
#define NEB  (NE/MB)             // 5000 blocks (exact)

#define DG_PLAIN 0
#define DG_SPLIT 1
#define DG_2A    2

typedef __attribute__((ext_vector_type(8))) short short8;
typedef __attribute__((ext_vector_type(4))) float f32x4;

struct CvtPtrs { const float* p[15]; };

__device__ __forceinline__ float silu_f(float v){ return v / (1.f + __expf(-v)); }
__device__ __forceinline__ float sigm_f(float v){ return 1.f / (1.f + __expf(-v)); }
__device__ __forceinline__ __half2 silu2(__half2 x){
    __half2 e = h2exp2(__hmul2(x, __float2half2_rn(-1.442695041f)));
    __half2 d = __hadd2(e, __float2half2_rn(1.0f));
    return __hmul2(x, h2rcp(d));
}
__device__ __forceinline__ __half2 h2shfl_xor_add(__half2 v, int m){
    int pi = *(int*)&v;
    pi = __shfl_xor(pi, m, 64);
    __half2 q = *(__half2*)&pi;
    return __hadd2(v, q);
}
// XCD-aware swizzle: consecutive logical blocks land on the SAME XCD so the
// shared agg/Hrow lines stay in one per-XCD L2 (dispatch is round-robin i%8).
__device__ __forceinline__ int xcd_logical(int bid, int nblk){
    int per = nblk >> 3;                 // nblk divisible by 8
    return (bid & 7) * per + (bid >> 3);
}

// ---- CSR build -------------------------------------------------------------
__global__ __launch_bounds__(256) void k_count(const int* __restrict__ row, int* __restrict__ cnt){
    int e = blockIdx.x * 256 + threadIdx.x;
    if (e < NE) atomicAdd(&cnt[row[e]], 1);
}

__global__ __launch_bounds__(1024) void k_scan(const int* __restrict__ cnt, int* __restrict__ rs, int* __restrict__ cur){
    __shared__ int sums[1024];
    const int PER = 10;                 // 1024*10 = 10240 >= NN
    int t = threadIdx.x;
    int base = t * PER;
    int s = 0;
    for (int i = 0; i < PER; i++){
        int idx = base + i;
        s += (idx < NN) ? cnt[idx] : 0;
    }
    sums[t] = s;
    __syncthreads();
    for (int off = 1; off < 1024; off <<= 1){
        int v = (t >= off) ? sums[t - off] : 0;
        __syncthreads();
        sums[t] += v;
        __syncthreads();
    }
    int run = (t == 0) ? 0 : sums[t - 1];
    for (int i = 0; i < PER; i++){
        int idx = base + i;
        if (idx < NN){
            int c = cnt[idx];
            rs[idx] = run;
            cur[idx] = run;
            run += c;
        }
    }
    if (t == 1023) rs[NN] = sums[1023];
}

__global__ __launch_bounds__(256) void k_fill(const int* __restrict__ row, int* __restrict__ cur, int* __restrict__ perm){
    int e = blockIdx.x * 256 + threadIdx.x;
    if (e < NE){
        int p = atomicAdd(&cur[row[e]], 1);
        perm[p] = e;
    }
}

// ---- combined prep ---------------------------------------------------------
// blocks [0,120): coalesced LDS-tiled transpose of 15 weight chunks into
//   MFMA-B-fragment order fp16. Block b: mat = b/8, kk = b%8.
// blocks [120,1370): h fp32 -> fp16 mirror.
__global__ __launch_bounds__(256) void k_prep(CvtPtrs pp, __half* __restrict__ dst,
                                              const float* __restrict__ hsrc, __half* __restrict__ h16){
    int bid = blockIdx.x, t = threadIdx.x;
    if (bid < 120){
        __shared__ __half lh[32 * 256];     // rows k=kk*32..+32, cols 0..255
        int mat = bid >> 3, kk = bid & 7;
        const float* src = pp.p[mat] + (size_t)kk * 32 * 256;
        #pragma unroll
        for (int i = 0; i < 32; i++)
            lh[i * 256 + t] = __float2half_rn(src[i * 256 + t]);   // coalesced
        __syncthreads();
        __half* db = dst + (size_t)mat * 65536 + kk * 512;
        int lane = t >> 2;
        int j0   = (t * 2) & 7;
        int i0   = (lane >> 4) * 8 + j0;    // k - kk*32
        int ncol = lane & 15;
        #pragma unroll
        for (int nt = 0; nt < 16; nt++){
            __half v0 = lh[i0 * 256 + nt * 16 + ncol];
            __half v1 = lh[(i0 + 1) * 256 + nt * 16 + ncol];
            unsigned int u = (unsigned int)*(unsigned short*)&v0 |
                             ((unsigned int)*(unsigned short*)&v1 << 16);
            *(unsigned int*)&db[nt * 4096 + t * 2] = u;            // coalesced
        }
    } else {
        int i = ((bid - 120) * 256 + t) * 8;      // NN*HID = 2.56M
        float4 f0 = *(const float4*)&hsrc[i];
        float4 f1 = *(const float4*)&hsrc[i + 4];
        uint4 o; __half2* op = (__half2*)&o;
        op[0] = __float22half2_rn(make_float2(f0.x, f0.y));
        op[1] = __float22half2_rn(make_float2(f0.z, f0.w));
        op[2] = __float22half2_rn(make_float2(f1.x, f1.y));
        op[3] = __float22half2_rn(make_float2(f1.z, f1.w));
        *(uint4*)&h16[i] = o;
    }
}

// ---- MFMA dense GEMM (XOR-swizzled LDS, M=64 tile) ------------------------
__global__ __launch_bounds__(256, 4) void k_dgemm(
        const __half* __restrict__ A1, const float* __restrict__ A2f,
        const __half* __restrict__ wpool, int wAidx, int wBidx,
        const float* __restrict__ bias, const float* __restrict__ R,
        float* __restrict__ out32, __half* __restrict__ out16,
        __half* __restrict__ outB16, float* __restrict__ zbuf, int mode, int act){
    __shared__ __half alds[64 * 256];
    int tid = threadIdx.x;
    int lid = tid & 63, w = tid >> 6;
    int quad = lid >> 4, l15 = lid & 15;
    int rb = blockIdx.x * 64;
    int by = blockIdx.y;
    int xorv = l15 & 7;

    // folded aggb zeroing (SPLIT layers only): each (row,col) zeroed once
    if (mode == DG_SPLIT && zbuf && by < 2){
        int sr2 = tid >> 5, cz = (tid & 31) * 4;
        #pragma unroll
        for (int it = 0; it < 8; it++){
            int rg = rb + it * 8 + sr2;
            if (rg < NN){
                float4 z4 = {0.f, 0.f, 0.f, 0.f};
                *(float4*)&zbuf[(size_t)rg * HID + by * 128 + cz] = z4;
            }
        }
    }

    float bv[2]; int cg0[2];
    #pragma unroll
    for (int n = 0; n < 2; n++){
        int cg = by * 128 + w * 32 + n * 16 + l15;
        cg0[n] = cg;
        bv[n] = (bias && cg < 256) ? bias[cg] : 0.f;
    }
    f32x4 acc[4][2];
    #pragma unroll
    for (int m = 0; m < 4; m++)
        #pragma unroll
        for (int n = 0; n < 2; n++){ f32x4 z = {bv[n], bv[n], bv[n], bv[n]}; acc[m][n] = z; }

    int npass = (mode == DG_2A) ? 2 : 1;
    int sr = tid >> 5;
    int c0 = (tid & 31) * 8;                       // logical column
    int pc = (((tid & 31) ^ sr) * 8);              // physical (swizzled) LDS column
    for (int pass = 0; pass < npass; pass++){
        if (pass) __syncthreads();
        int widx, byl = by;
        if (mode == DG_SPLIT){ if (by >= 2){ widx = wBidx; byl = by - 2; } else widx = wAidx; }
        else widx = pass ? wBidx : wAidx;
        const short8* bbase = (const short8*)(wpool + (size_t)widx * 65536);

        if (pass == 0){
            #pragma unroll
            for (int it = 0; it < 8; it++){
                int r = it * 8 + sr;
                int rr = rb + r; if (rr > NN - 1) rr = NN - 1;
                *(uint4*)&alds[r * 256 + pc] = *(const uint4*)&A1[(size_t)rr * HID + c0];
            }
        } else {
            #pragma unroll
            for (int it = 0; it < 8; it++){
                int r = it * 8 + sr;
                int rr = rb + r; if (rr > NN - 1) rr = NN - 1;
                float4 f0 = *(const float4*)&A2f[(size_t)rr * HID + c0];
                float4 f1 = *(const float4*)&A2f[(size_t)rr * HID + c0 + 4];
                uint4 o; __half2* op = (__half2*)&o;
                op[0] = __float22half2_rn(make_float2(f0.x, f0.y));
                op[1] = __float22half2_rn(make_float2(f0.z, f0.w));
                op[2] = __float22half2_rn(make_float2(f1.x, f1.y));
                op[3] = __float22half2_rn(make_float2(f1.z, f1.w));
                *(uint4*)&alds[r * 256 + pc] = o;
            }
        }
        __syncthreads();
        #pragma unroll
        for (int kk = 0; kk < 8; kk++){
            short8 bf[2];
            #pragma unroll
            for (int n = 0; n < 2; n++)
                bf[n] = bbase[((byl * 8 + w * 2 + n) * 8 + kk) * 64 + lid];
            #pragma unroll
            for (int m = 0; m < 4; m++){
                const short8 af = *(const short8*)&alds[(m * 16 + l15) * 256 + (((kk * 4 + quad) ^ xorv) * 8)];
                #pragma unroll
                for (int n = 0; n < 2; n++)
                    acc[m][n] = __builtin_amdgcn_mfma_f32_16x16x32_f16(af, bf[n], acc[m][n], 0, 0, 0);
            }
        }
    }
    #pragma unroll
    for (int n = 0; n < 2; n++){
        int cg = cg0[n];
        #pragma unroll
        for (int m = 0; m < 4; m++){
            #pragma unroll
            for (int r = 0; r < 4; r++){
                int rg = rb + m * 16 + quad * 4 + r;
                if (rg < NN){
                    float v = acc[m][n][r];
                    if (act) v = silu_f(v);
                    if (R) v += R[(size_t)rg * HID + cg];
                    if (mode == DG_SPLIT){
                        if (cg < 256) out16[(size_t)rg * HID + cg] = __float2half_rn(v);
                        else          outB16[(size_t)rg * HID + cg - 256] = __float2half_rn(v);
                    } else {
                        if (out32) out32[(size_t)rg * HID + cg] = v;
                        if (out16) out16[(size_t)rg * HID + cg] = __float2half_rn(v);
                    }
                }
            }
        }
    }
}

// ---- MFMA edge kernel (GCL): 64 perm-ordered edges per block --------------
__global__ __launch_bounds__(256, 4) void k_edge_mfma(
        const __half* __restrict__ HrowB, const __half* __restrict__ HcolB,
        const int* __restrict__ row, const int* __restrict__ col,
        const float* __restrict__ ea, const int* __restrict__ perm,
        const __half* __restrict__ w2f,
        const float* __restrict__ w512, const float* __restrict__ w513,
        const float* __restrict__ eb2, const float* __restrict__ aw, const float* __restrict__ ab,
        float* __restrict__ agg){
    __shared__ __half vlds[MB * 256];
    __shared__ unsigned int attp2[4][MB / 2];
    __shared__ float attf[MB];
    __shared__ int   nrows[MB];
    __shared__ int   cids[MB];
    __shared__ float ea0s[MB], ea1s[MB];

    int tid = threadIdx.x;
    int e0  = xcd_logical(blockIdx.x, NEB) * MB;
    float ab0 = ab[0];
    if (tid < MB){
        int eid = perm[e0 + tid];
        nrows[tid] = row[eid];
        cids[tid]  = col[eid];
        ea0s[tid]  = ea[eid * 2 + 0];
        ea1s[tid]  = ea[eid * 2 + 1];
    }
    __syncthreads();
    {   // staging with full gather-hoist: all 16 loads in flight before compute
        int sr = tid >> 5;
        int c0 = (tid & 31) * 8;
        int pc = ((tid & 31) ^ sr) * 8;            // swizzled LDS chunk
        int nidv[8], cidv[8];
        float ea0v[8], ea1v[8];
        #pragma unroll
        for (int it = 0; it < 8; it++){
            int r = it * 8 + sr;
            nidv[it] = nrows[r]; cidv[it] = cids[r];
            ea0v[it] = ea0s[r];  ea1v[it] = ea1s[r];
        }
        uint4 hrv[8], hcv[8];
        #pragma unroll
        for (int it = 0; it < 8; it++){
            hrv[it] = *(const uint4*)&HrowB[(size_t)nidv[it] * HID + c0];
            hcv[it] = *(const uint4*)&HcolB[(size_t)cidv[it] * HID + c0];
        }
        float4 wa = *(const float4*)&w512[c0];
        float4 wb = *(const float4*)&w512[c0 + 4];
        float4 ua = *(const float4*)&w513[c0];
        float4 ub = *(const float4*)&w513[c0 + 4];
        __half2 w5h[4] = {__float22half2_rn(make_float2(wa.x, wa.y)), __float22half2_rn(make_float2(wa.z, wa.w)),
                          __float22half2_rn(make_float2(wb.x, wb.y)), __float22half2_rn(make_float2(wb.z, wb.w))};
        __half2 w6h[4] = {__float22half2_rn(make_float2(ua.x, ua.y)), __float22half2_rn(make_float2(ua.z, ua.w)),
                          __float22half2_rn(make_float2(ub.x, ub.y)), __float22half2_rn(make_float2(ub.z, ub.w))};
        #pragma unroll
        for (int it = 0; it < 8; it++){
            int r = it * 8 + sr;
            __half2 e0h = __float2half2_rn(ea0v[it]);
            __half2 e1h = __float2half2_rn(ea1v[it]);
            const __half2* hrp = (const __half2*)&hrv[it];
            const __half2* hcp = (const __half2*)&hcv[it];
            uint4 o; __half2* op = (__half2*)&o;
            #pragma unroll
            for (int q = 0; q < 4; q++){
                __half2 t = __hadd2(hrp[q], hcp[q]);
                t = __hfma2(e0h, w5h[q], t);
                t = __hfma2(e1h, w6h[q], t);
                op[q] = silu2(t);
            }
            *(uint4*)&vlds[r * 256 + pc] = o;
        }
    }
    __syncthreads();

    int lid = tid & 63, w = tid >> 6;
    int quad = lid >> 4, l15 = lid & 15;
    int xorv = l15 & 7;

    float b2v[4]; __half2 aw2[4];
    #pragma unroll
    for (int n = 0; n < 4; n++){
        int cg = w * 64 + n * 16 + l15;
        b2v[n] = eb2[cg];
        aw2[n] = __float2half2_rn(aw[cg]);
    }
    f32x4 acc[4][4];
    #pragma unroll
    for (int m = 0; m < 4; m++)
        #pragma unroll
        for (int n = 0; n < 4; n++){ f32x4 z = {b2v[n], b2v[n], b2v[n], b2v[n]}; acc[m][n] = z; }

    const short8* bbase = (const short8*)w2f;
    #pragma unroll
    for (int kk = 0; kk < 8; kk++){
        short8 bf[4];
        #pragma unroll
        for (int n = 0; n < 4; n++)
            bf[n] = bbase[((w * 4 + n) * 8 + kk) * 64 + lid];
        #pragma unroll
        for (int m = 0; m < 4; m++){
            const short8 af = *(const short8*)&vlds[(m * 16 + l15) * 256 + (((kk * 4 + quad) ^ xorv) * 8)];
            #pragma unroll
            for (int n = 0; n < 4; n++)
                acc[m][n] = __builtin_amdgcn_mfma_f32_16x16x32_f16(af, bf[n], acc[m][n], 0, 0, 0);
        }
    }

    // packed epilogue: mij = silu2(pack(acc)); attention partials in fp16
    __half2 mijp[4][4][2];          // [m][n][pair]: (r0,r1),(r2,r3)
    #pragma unroll
    for (int m = 0; m < 4; m++){
        __half2 p2a = __float2half2_rn(0.f), p2b = p2a;
        #pragma unroll
        for (int n = 0; n < 4; n++){
            __half2 ha = silu2(__float22half2_rn(make_float2(acc[m][n][0], acc[m][n][1])));
            __half2 hb = silu2(__float22half2_rn(make_float2(acc[m][n][2], acc[m][n][3])));
            mijp[m][n][0] = ha; mijp[m][n][1] = hb;
            p2a = __hfma2(ha, aw2[n], p2a);
            p2b = __hfma2(hb, aw2[n], p2b);
        }
        p2a = h2shfl_xor_add(p2a, 1); p2a = h2shfl_xor_add(p2a, 2);
        p2a = h2shfl_xor_add(p2a, 4); p2a = h2shfl_xor_add(p2a, 8);
        p2b = h2shfl_xor_add(p2b, 1); p2b = h2shfl_xor_add(p2b, 2);
        p2b = h2shfl_xor_add(p2b, 4); p2b = h2shfl_xor_add(p2b, 8);
        if (l15 == 0){
            attp2[w][m * 8 + quad * 2 + 0] = *(unsigned int*)&p2a;
            attp2[w][m * 8 + quad * 2 + 1] = *(unsigned int*)&p2b;
        }
    }
    __syncthreads();
    if (tid < MB){
        int pr = tid >> 1;
        unsigned int u0 = attp2[0][pr], u1 = attp2[1][pr], u2 = attp2[2][pr], u3 = attp2[3][pr];
        __half2 h0 = *(__half2*)&u0, h1 = *(__half2*)&u1, h2 = *(__half2*)&u2, h3 = *(__half2*)&u3;
        float lo = __low2float(h0) + __low2float(h1) + __low2float(h2) + __low2float(h3);
        float hi = __high2float(h0) + __high2float(h1) + __high2float(h2) + __high2float(h3);
        float a0 = ((tid & 1) ? hi : lo) + ab0;
        attf[tid] = 0.01f * sigm_f(a0);     // fold /NORM_FACTOR into att
    }
    __syncthreads();

    // segment-sum agg (rows CSR-sorted); fast path: whole 16-tile one segment
    for (int m = 0; m < 4; m++){
        int mb = m * 16;
        __half2 at2a = __float22half2_rn(make_float2(attf[mb + quad * 4 + 0], attf[mb + quad * 4 + 1]));
        __half2 at2b = __float22half2_rn(make_float2(attf[mb + quad * 4 + 2], attf[mb + quad * 4 + 3]));
        int rA = nrows[mb], rB = nrows[mb + 15];
        if (rA == rB){
            #pragma unroll
            for (int n = 0; n < 4; n++){
                __half2 s2 = __hmul2(mijp[m][n][0], at2a);
                s2 = __hfma2(mijp[m][n][1], at2b, s2);
                float s = __low2float(s2) + __high2float(s2);
                s += __shfl_xor(s, 16);
                s += __shfl_xor(s, 32);
                if (lid < 16)
                    atomicAdd(&agg[(size_t)rA * HID + w * 64 + n * 16 + lid], s);
            }
        } else {
            float ef[4][4]; int nv[4];
            #pragma unroll
            for (int r = 0; r < 4; r++) nv[r] = nrows[mb + quad * 4 + r];
            #pragma unroll
            for (int n = 0; n < 4; n++){
                __half2 ea2 = __hmul2(mijp[m][n][0], at2a);
                __half2 eb2h = __hmul2(mijp[m][n][1], at2b);
                ef[n][0] = __low2float(ea2);  ef[n][1] = __high2float(ea2);
                ef[n][2] = __low2float(eb2h); ef[n][3] = __high2float(eb2h);
            }
            int myn = nrows[mb + l15];
            int t16 = 0;
            while (t16 < 16){
                int tgt = nrows[mb + t16];
                unsigned long long bal = __ballot((lid < 16) && (lid > t16) && (myn != tgt));
                int nxt = bal ? (__ffsll((unsigned long long)bal) - 1) : 16;
                #pragma unroll
                for (int n = 0; n < 4; n++){
                    float s = 0.f;
                    #pragma unroll
                    for (int r = 0; r < 4; r++)
                        s += (nv[r] == tgt) ? ef[n][r] : 0.f;
                    s += __shfl_xor(s, 16);
                    s += __shfl_xor(s, 32);
                    if (lid < 16)
                        atomicAdd(&agg[(size_t)tgt * HID + w * 64 + n * 16 + lid], s);
                }
                t16 = nxt;
            }
        }
    }
}

// ---- MFMA coord kernel: same GEMM, epilogue -> per-edge phi ---------------
__global__ __launch_bounds__(256, 4) void k_coord_mfma(
        const __half* __restrict__ CrowB, const __half* __restrict__ CcolB,
        const int* __restrict__ row, const int* __restrict__ col,
        const float* __restrict__ ea, const int* __restrict__ perm,
        const __half* __restrict__ w2f,
        const float* __restrict__ w512, const float* __restrict__ w513,
        const float* __restrict__ cb2, const float* __restrict__ cw3,
        float* __restrict__ phi){
    __shared__ __half vlds[MB * 256];
    __shared__ unsigned int pp2[4][MB / 2];
    __shared__ int   nrows[MB];
    __shared__ int   cids[MB];
    __shared__ float ea0s[MB], ea1s[MB];

    int tid = threadIdx.x;
    int e0  = xcd_logical(blockIdx.x, NEB) * MB;
    if (tid < MB){
        int eid = perm[e0 + tid];
        nrows[tid] = row[eid];
        cids[tid]  = col[eid];
        ea0s[tid]  = ea[eid * 2 + 0];
        ea1s[tid]  = ea[eid * 2 + 1];
    }
    __syncthreads();
    {   // staging with full gather-hoist
        int sr = tid >> 5;
        int c0 = (tid & 31) * 8;
        int pc = ((tid & 31) ^ sr) * 8;
        int nidv[8], cidv[8];
        float ea0v[8], ea1v[8];
        #pragma unroll
        for (int it = 0; it < 8; it++){
            int r = it * 8 + sr;
            nidv[it] = nrows[r]; cidv[it] = cids[r];
            ea0v[it] = ea0s[r];  ea1v[it] = ea1s[r];
        }
        uint4 hrv[8], hcv[8];
        #pragma unroll
        for (int it = 0; it < 8; it++){
            hrv[it] = *(const uint4*)&CrowB[(size_t)nidv[it] * HID + c0];
            hcv[it] = *(const uint4*)&CcolB[(size_t)cidv[it] * HID + c0];
        }
        float4 wa = *(const float4*)&w512[c0];
        float4 wb = *(const float4*)&w512[c0 + 4];
        float4 ua = *(const float4*)&w513[c0];
        float4 ub = *(const float4*)&w513[c0 + 4];
        __half2 w5h[4] = {__float22half2_rn(make_float2(wa.x, wa.y)), __float22half2_rn(make_float2(wa.z, wa.w)),
                          __float22half2_rn(make_float2(wb.x, wb.y)), __float22half2_rn(make_float2(wb.z, wb.w))};
        __half2 w6h[4] = {__float22half2_rn(make_float2(ua.x, ua.y)), __float22half2_rn(make_float2(ua.z, ua.w)),
                          __float22half2_rn(make_float2(ub.x, ub.y)), __float22half2_rn(make_float2(ub.z, ub.w))};
        #pragma unroll
        for (int it = 0; it < 8; it++){
            int r = it * 8 + sr;
            __half2 e0h = __float2half2_rn(ea0v[it]);
            __half2 e1h = __float2half2_rn(ea1v[it]);
            const __half2* hrp = (const __half2*)&hrv[it];
            const __half2* hcp = (const __half2*)&hcv[it];
            uint4 o; __half2* op = (__half2*)&o;
            #pragma unroll
            for (int q = 0; q < 4; q++){
                __half2 t = __hadd2(hrp[q], hcp[q]);
                t = __hfma2(e0h, w5h[q], t);
                t = __hfma2(e1h, w6h[q], t);
                op[q] = silu2(t);
            }
            *(uint4*)&vlds[r * 256 + pc] = o;
        }
    }
    __syncthreads();

    int lid = tid & 63, w = tid >> 6;
    int quad = lid >> 4, l15 = lid & 15;
    int xorv = l15 & 7;

    float b2v[4]; __half2 w32[4];
    #pragma unroll
    for (int n = 0; n < 4; n++){
        int cg = w * 64 + n * 16 + l15;
        b2v[n] = cb2[cg];
        w32[n] = __float2half2_rn(cw3[cg]);
    }
    f32x4 acc[4][4];
    #pragma unroll
    for (int m = 0; m < 4; m++)
        #pragma unroll
        for (int n = 0; n < 4; n++){ f32x4 z = {b2v[n], b2v[n], b2v[n], b2v[n]}; acc[m][n] = z; }

    const short8* bbase = (const short8*)w2f;
    #pragma unroll
    for (int kk = 0; kk < 8; kk++){
        short8 bf[4];
        #pragma unroll
        for (int n = 0; n < 4; n++)
            bf[n] = bbase[((w * 4 + n) * 8 + kk) * 64 + lid];
        #pragma unroll
        for (int m = 0; m < 4; m++){
            const short8 af = *(const short8*)&vlds[(m * 16 + l15) * 256 + (((kk * 4 + quad) ^ xorv) * 8)];
            #pragma unroll
            for (int n = 0; n < 4; n++)
                acc[m][n] = __builtin_amdgcn_mfma_f32_16x16x32_f16(af, bf[n], acc[m][n], 0, 0, 0);
        }
    }

    #pragma unroll
    for (int m = 0; m < 4; m++){
        __half2 p2a = __float2half2_rn(0.f), p2b = p2a;
        #pragma unroll
        for (int n = 0; n < 4; n++){
            __half2 ha = silu2(__float22half2_rn(make_float2(acc[m][n][0], acc[m][n][1])));
            __half2 hb = silu2(__float22half2_rn(make_float2(acc[m][n][2], acc[m][n][3])));
            p2a = __hfma2(ha, w32[n], p2a);
            p2b = __hfma2(hb, w32[n], p2b);
        }
        p2a = h2shfl_xor_add(p2a, 1); p2a = h2shfl_xor_add(p2a, 2);
        p2a = h2shfl_xor_add(p2a, 4); p2a = h2shfl_xor_add(p2a, 8);
        p2b = h2shfl_xor_add(p2b, 1); p2b = h2shfl_xor_add(p2b, 2);
        p2b = h2shfl_xor_add(p2b, 4); p2b = h2shfl_xor_add(p2b, 8);
        if (l15 == 0){
            pp2[w][m * 8 + quad * 2 + 0] = *(unsigned int*)&p2a;
            pp2[w][m * 8 + quad * 2 + 1] = *(unsigned int*)&p2b;
        }
    }
    __syncthreads();
    if (tid < MB){
        int pr = tid >> 1;
        unsigned int u0 = pp2[0][pr], u1 = pp2[1][pr], u2 = pp2[2][pr], u3 = pp2[3][pr];
        __half2 h0 = *(__half2*)&u0, h1 = *(__half2*)&u1, h2 = *(__half2*)&u2, h3 = *(__half2*)&u3;
        float lo = __low2float(h0) + __low2float(h1) + __low2float(h2) + __low2float(h3);
        float hi = __high2float(h0) + __high2float(h1) + __high2float(h2) + __high2float(h3);
        phi[e0 + tid] = (tid & 1) ? hi : lo;
    }
}

// ---- coordinate segment-sum: one wave per node ----------------------------
__global__ __launch_bounds__(64) void k_xupd(const float* __restrict__ x, const float* __restrict__ phi,
                                             const int* __restrict__ col, const int* __restrict__ perm,
                                             const int* __restrict__ rs, float* __restrict__ xout){
    int n = blockIdx.x, lid = threadIdx.x;
    int s = rs[n], e = rs[n + 1];
    float x0 = x[n * 3 + 0], x1 = x[n * 3 + 1], x2 = x[n * 3 + 2];
    float tx = 0.f, ty = 0.f, tz = 0.f;
    for (int i = s + lid; i < e; i += 64){
        int eid = perm[i];
        int c = col[eid];
        float d0 = x0 - x[c * 3 + 0];
        float d1 = x1 - x[c * 3 + 1];
        float d2 = x2 - x[c * 3 + 2];
        float r2 = d0 * d0 + d1 * d1 + d2 * d2;
        float f  = phi[i] / (sqrtf(r2 + 1e-8f) + 1.f);   // NORM_CONST = 1
        tx += d0 * f; ty += d1 * f; tz += d2 * f;
    }
    for (int o = 32; o; o >>= 1){
        tx += __shfl_down(tx, o);
        ty += __shfl_down(ty, o);
        tz += __shfl_down(tz, o);
    }
    if (lid == 0){
        xout[n * 3 + 0] = x0 + 0.01f * tx;
        xout[n * 3 + 1] = x1 + 0.01f * ty;
        xout[n * 3 + 2] = x2 + 0.01f * tz;
    }
}

// ---------------------------------------------------------------------------
extern "C" void kernel_launch(void* const* d_in, const int* in_sizes, int n_in,
                              void* d_out, int out_size, void* d_ws, size_t ws_size,
                              hipStream_t stream){
    const float* h  = (const float*)d_in[0];
    const float* x  = (const float*)d_in[1];
    const int*   ei = (const int*)d_in[2];
    const float* ea = (const float*)d_in[3];
    const int* rowp = ei;
    const int* colp = ei + NE;

    const float* ew1[2] = {(const float*)d_in[4],  (const float*)d_in[14]};
    const float* eb1[2] = {(const float*)d_in[5],  (const float*)d_in[15]};
    const float* ew2[2] = {(const float*)d_in[6],  (const float*)d_in[16]};
    const float* eb2[2] = {(const float*)d_in[7],  (const float*)d_in[17]};
    const float* nw1[2] = {(const float*)d_in[8],  (const float*)d_in[18]};
    const float* nb1[2] = {(const float*)d_in[9],  (const float*)d_in[19]};
    const float* nw2[2] = {(const float*)d_in[10], (const float*)d_in[20]};
    const float* nb2[2] = {(const float*)d_in[11], (const float*)d_in[21]};
    const float* aw[2]  = {(const float*)d_in[12], (const float*)d_in[22]};
    const float* ab[2]  = {(const float*)d_in[13], (const float*)d_in[23]};
    const float* cw1 = (const float*)d_in[24];
    const float* cb1 = (const float*)d_in[25];
    const float* cw2 = (const float*)d_in[26];
    const float* cb2 = (const float*)d_in[27];
    const float* cw3 = (const float*)d_in[28];

    char* w = (char*)d_ws;
    auto alloc = [&](size_t bytes){ void* p = (void*)w; w += (bytes + 255) & ~((size_t)255); return p; };
    int* rs    = (int*)alloc((NN + 1) * sizeof(int));
    int* cur   = (int*)alloc(NN * sizeof(int));
    int* perm  = (int*)alloc(NE * sizeof(int));
    __half* HrowB = (__half*)alloc((size_t)NN * HID * sizeof(__half));
    __half* HcolB = (__half*)alloc((size_t)NN * HID * sizeof(__half));
    float*  aggb  = (float*)alloc((size_t)NN * HID * sizeof(float));
    __half* wfrag = (__half*)alloc((size_t)15 * HID * HID * sizeof(__half));
    float*  phi   = (float*)alloc((size_t)NE * sizeof(float));
    __half* h16   = (__half*)alloc((size_t)NN * HID * sizeof(__half));
    __half* Tb16  = HrowB;   // HrowB dead after edge kernel; reuse for node-MLP hidden

    float* hout = (float*)d_out;            // [NN,HID]
    float* xout = hout + (size_t)NN * HID;  // [NN,3]

    // CSR build + conversions
    hipMemsetAsync(cur, 0, NN * sizeof(int), stream);
    k_count<<<(NE + 255) / 256, 256, 0, stream>>>(rowp, cur);
    k_scan<<<1, 1024, 0, stream>>>(cur, rs, cur);
    k_fill<<<(NE + 255) / 256, 256, 0, stream>>>(rowp, cur, perm);

    CvtPtrs cp;
    for (int l = 0; l < 2; l++){
        cp.p[l * 5 + 0] = ew1[l];
        cp.p[l * 5 + 1] = ew1[l] + 256 * HID;
        cp.p[l * 5 + 2] = nw1[l];
        cp.p[l * 5 + 3] = nw1[l] + 256 * HID;
        cp.p[l * 5 + 4] = nw2[l];
    }
    cp.p[10] = cw1;
    cp.p[11] = cw1 + 256 * HID;
    cp.p[12] = ew2[0];
    cp.p[13] = ew2[1];
    cp.p[14] = cw2;
    k_prep<<<1370, 256, 0, stream>>>(cp, wfrag, h, h16);

    dim3 g2(157, 2), g4(157, 4);
    const float* hres = h;
    for (int l = 0; l < 2; l++){
        // [Hrow|Hcol] = h@[ew1a|ew1b] (+eb1 on first half), fp16 outs; zeroes aggb
        k_dgemm<<<g4, 256, 0, stream>>>(h16, nullptr, wfrag, l * 5 + 0, l * 5 + 1,
                                        eb1[l], nullptr, nullptr, HrowB, HcolB, aggb, DG_SPLIT, 0);
        k_edge_mfma<<<NEB, 256, 0, stream>>>(HrowB, HcolB, rowp, colp, ea, perm,
                                             wfrag + (size_t)(12 + l) * HID * HID,
                                             ew1[l] + 512 * HID, ew1[l] + 513 * HID,
                                             eb2[l], aw[l], ab[l], aggb);
        // T = silu(h@nw1a + agg@nw1b + nb1)  -> fp16
        k_dgemm<<<g2, 256, 0, stream>>>(h16, aggb, wfrag, l * 5 + 2, l * 5 + 3,
                                        nb1[l], nullptr, nullptr, Tb16, nullptr, nullptr, DG_2A, 1);
        // h = hres + T@nw2 + nb2  -> fp32 (d_out) + fp16 mirror
        k_dgemm<<<g2, 256, 0, stream>>>(Tb16, nullptr, wfrag, l * 5 + 4, 0,
                                        nb2[l], hres, hout, h16, nullptr, nullptr, DG_PLAIN, 0);
        hres = hout;
    }
    // coord update
    k_dgemm<<<g4, 256, 0, stream>>>(h16, nullptr, wfrag, 10, 11,
                                    cb1, nullptr, nullptr, HrowB, HcolB, nullptr, DG_SPLIT, 0);
    k_coord_mfma<<<NEB, 256, 0, stream>>>(HrowB, HcolB, rowp, colp, ea, perm,
                                          wfrag + (size_t)14 * HID * HID,
                                          cw1 + 512 * HID, cw1 + 513 * HID,
                                          cb2, cw3, phi);
    k_xupd<<<NN, 64, 0, stream>>>(x, phi, colp, perm, rs, xout);
}